// Round 1
// baseline (122.348 us; speedup 1.0000x reference)
//
#include <hip/hip_runtime.h>
#include <stdint.h>
#include <float.h>

#define BLK 256
#define IPT 8                 // owner points per thread (8 independent min-chains)
#define OWNERS (BLK * IPT)    // 2048 owners per block
#define SLICE 128             // scanned points per block (2 KB LDS)
#define SUB 64                // subtile granularity for deferred-index recovery
#define FPW 16                // owners recovered per wave in finalize

typedef unsigned long long ull;

// Monotone float -> uint transform (preserves <, total order) and inverse.
__device__ __forceinline__ unsigned int ford(float f) {
    int b = __float_as_int(f);
    return (b >= 0) ? ((unsigned)b ^ 0x80000000u) : ~(unsigned)b;
}
__device__ __forceinline__ float ford_inv(unsigned int u) {
    int b = (u & 0x80000000u) ? (int)(u ^ 0x80000000u) : (int)~u;
    return __int_as_float(b);
}

// Phase 1: min VALUE only. Candidates processed in PAIRS so the two fmins per
// pair fuse into one v_min3_f32 (8 -> 7 VALU instrs per 2 pairs). Min is exact
// (no rounding), so values / subtile-base logic / bit-exact recovery are
// unchanged vs the sequential-fmin version.
__global__ __launch_bounds__(BLK) void nn_min_dual(
    const float* __restrict__ p, const float* __restrict__ g,
    ull* __restrict__ rowmin, ull* __restrict__ colmin,
    int rowBlocks, int rowSlices, int colSlices)
{
    __shared__ float4 sb[SLICE];

    const float* A; const float* B; ull* outmin; int id, nSlices;
    if ((int)blockIdx.x < rowBlocks) {
        id = blockIdx.x;             A = p; B = g; outmin = rowmin; nSlices = rowSlices;
    } else {
        id = blockIdx.x - rowBlocks; A = g; B = p; outmin = colmin; nSlices = colSlices;
    }
    const int chunk = id / nSlices;
    const int slice = id - chunk * nSlices;
    const int s0 = slice * SLICE;

    // Stage slice (coords + |B|^2). Explicit fmaf: finalize recomputes the
    // identical expression so bit-exact equality holds.
    if (threadIdx.x < SLICE) {
        int s = s0 + threadIdx.x;
        float bx = B[3 * s], by = B[3 * s + 1], bz = B[3 * s + 2];
        float w = fmaf(bz, bz, fmaf(by, by, bx * bx));
        sb[threadIdx.x] = make_float4(bx, by, bz, w);
    }

    const int o0 = chunk * OWNERS + threadIdx.x;
    float ax[IPT], ay[IPT], az[IPT], best[IPT];
    int base[IPT];
#pragma unroll
    for (int r = 0; r < IPT; ++r) {
        int o = o0 + r * BLK;
        ax[r] = -2.0f * A[3 * o];
        ay[r] = -2.0f * A[3 * o + 1];
        az[r] = -2.0f * A[3 * o + 2];
        best[r] = FLT_MAX;
        base[r] = s0;
    }
    __syncthreads();

    for (int st = 0; st < SLICE; st += SUB) {
        float prev[IPT];
#pragma unroll
        for (int r = 0; r < IPT; ++r) prev[r] = best[r];
#pragma unroll 2
        for (int k = st; k < st + SUB; k += 2) {
            float4 q0 = sb[k];        // wave-uniform broadcast reads
            float4 q1 = sb[k + 1];
#pragma unroll
            for (int r = 0; r < IPT; ++r) {
                float v0 = fmaf(ax[r], q0.x, fmaf(ay[r], q0.y, fmaf(az[r], q0.z, q0.w)));
                float v1 = fmaf(ax[r], q1.x, fmaf(ay[r], q1.y, fmaf(az[r], q1.z, q1.w)));
                best[r] = fminf(fminf(v0, v1), best[r]);   // -> v_min3_f32
            }
        }
#pragma unroll
        for (int r = 0; r < IPT; ++r)
            if (best[r] < prev[r]) base[r] = s0 + st;   // strict <: first subtile wins
    }

#pragma unroll
    for (int r = 0; r < IPT; ++r) {
        ull packed = ((ull)ford(best[r]) << 32) | (unsigned)base[r];
        atomicMin(&outmin[o0 + r * BLK], packed);
    }
}

// Phase 2 + finalize, wave-parallel: one wave recovers one owner at a time.
// Lane j recomputes the bit-identical fma chain for candidate base+j; ballot +
// ffs picks the FIRST matching index (same semantics as the serial break).
// 16 owners per wave, block-partial sum, one atomicAdd per block.
__global__ __launch_bounds__(BLK) void finalize_kernel(
    const ull* __restrict__ rowmin, const ull* __restrict__ colmin,
    const float* __restrict__ p, const float* __restrict__ g,
    const float* __restrict__ pn, const float* __restrict__ gn,
    float* __restrict__ out, int N, int M, float invN, float invM)
{
    const int lane = threadIdx.x & 63;
    const int waveInBlk = threadIdx.x >> 6;
    const int wave = blockIdx.x * (BLK / 64) + waveInBlk;
    const int t0 = wave * FPW;
    float c = 0.0f;

#pragma unroll 1
    for (int u = 0; u < FPW; ++u) {
        int t = t0 + u;                     // wave-uniform
        if (t >= N + M) break;
        const float* A; const float* B; const float* An; const float* Bn;
        ull packed; int o; float inv;
        if (t < N) { o = t;     A = p; B = g; An = pn; Bn = gn; packed = rowmin[o]; inv = invN; }
        else       { o = t - N; A = g; B = p; An = gn; Bn = pn; packed = colmin[o]; inv = invM; }

        float ax = -2.0f * A[3 * o];
        float ay = -2.0f * A[3 * o + 1];
        float az = -2.0f * A[3 * o + 2];
        float bestf = ford_inv((unsigned int)(packed >> 32));
        int base = (int)(packed & 0xffffffffull);

        int s = base + lane;                // 64 candidates scanned in parallel
        float bx = B[3 * s], by = B[3 * s + 1], bz = B[3 * s + 2];
        float w = fmaf(bz, bz, fmaf(by, by, bx * bx));
        float v = fmaf(ax, bx, fmaf(ay, by, fmaf(az, bz, w)));

        ull m = __ballot(v == bestf);       // bit-exact recompute; >=1 lane matches
        int j = (m != 0ull) ? (__ffsll(m) - 1) : 0;   // first index wins
        if (lane == j) {
            int idx = base + j;
            float d = An[3 * o] * Bn[3 * idx] + An[3 * o + 1] * Bn[3 * idx + 1]
                    + An[3 * o + 2] * Bn[3 * idx + 2];
            c += (1.0f - d) * inv;
        }
    }

#pragma unroll
    for (int off = 32; off > 0; off >>= 1) c += __shfl_down(c, off, 64);
    __shared__ float partial[BLK / 64];
    if (lane == 0) partial[waveInBlk] = c;
    __syncthreads();
    if (threadIdx.x == 0) {
        float s = 0.0f;
#pragma unroll
        for (int w = 0; w < BLK / 64; ++w) s += partial[w];
        atomicAdd(out, s);
    }
}

extern "C" void kernel_launch(void* const* d_in, const int* in_sizes, int n_in,
                              void* d_out, int out_size, void* d_ws, size_t ws_size,
                              hipStream_t stream) {
    const float* p  = (const float*)d_in[0];   // [N,3] predicted points
    const float* pn = (const float*)d_in[1];   // [N,3] predicted normals (unit)
    const float* g  = (const float*)d_in[2];   // [M,3] gt points
    const float* gn = (const float*)d_in[3];   // [M,3] gt normals (unit)
    const int N = in_sizes[0] / 3;             // 8192
    const int M = in_sizes[2] / 3;             // 32768

    ull* rowmin = (ull*)d_ws;                  // [N]
    ull* colmin = rowmin + N;                  // [M]
    float* out = (float*)d_out;

    hipMemsetAsync(d_ws, 0xFF, (size_t)(N + M) * sizeof(ull), stream);
    hipMemsetAsync(d_out, 0, sizeof(float), stream);

    const int rowSlices = M / SLICE;                 // 256
    const int colSlices = N / SLICE;                 // 64
    const int rowBlocks = (N / OWNERS) * rowSlices;  // 4*256  = 1024
    const int colBlocks = (M / OWNERS) * colSlices;  // 16*64  = 1024
    nn_min_dual<<<rowBlocks + colBlocks, BLK, 0, stream>>>(
        p, g, rowmin, colmin, rowBlocks, rowSlices, colSlices);

    const int totOwners = N + M;                     // 40960
    const int wavesNeeded = (totOwners + FPW - 1) / FPW;        // 2560
    const int finBlocks = (wavesNeeded + (BLK / 64) - 1) / (BLK / 64);  // 640
    finalize_kernel<<<finBlocks, BLK, 0, stream>>>(
        rowmin, colmin, p, g, pn, gn, out, N, M, 1.0f / N, 1.0f / M);
}